// Round 2
// baseline (634.073 us; speedup 1.0000x reference)
//
#include <hip/hip_runtime.h>
#include <stdint.h>

// Shapes (fixed by reference): B=32, S=2048, D=1024.
#define BDIM 32
#define SDIM 2048
#define DDIM 1024
#define MDIM (BDIM * SDIM)   // 65536 rows of the GEMM

typedef __bf16 bf16x8 __attribute__((ext_vector_type(8)));
typedef float  f32x4  __attribute__((ext_vector_type(4)));

// ---------- helpers ----------

__device__ inline unsigned short f2bf(float f) {
  union { float f; unsigned u; } un; un.f = f;
  unsigned r = un.u + 0x7fffu + ((un.u >> 16) & 1u);   // RNE
  return (unsigned short)(r >> 16);
}

__device__ inline float fast_tanh(float x) {
  float e = __expf(2.0f * x);
  return 1.0f - 2.0f / (e + 1.0f);
}

__device__ inline void gl_lds16(const unsigned short* g, unsigned short* l) {
  __builtin_amdgcn_global_load_lds(
      (__attribute__((address_space(1))) unsigned int*)(void*)(uintptr_t)g,
      (__attribute__((address_space(3))) unsigned int*)l,
      16, 0, 0);
}

// ---------- kernel 1: fp32 -> bf16 convert (W only, 8 elems/thread) ----------

__global__ __launch_bounds__(256) void cvt_kernel(const float* __restrict__ src,
                                                  unsigned short* __restrict__ dst) {
  size_t i = (size_t)blockIdx.x * 256 + threadIdx.x;
  const float4* s4 = (const float4*)src;
  float4 a = s4[2 * i];
  float4 b = s4[2 * i + 1];
  uint4 o;
  o.x = (unsigned)f2bf(a.x) | ((unsigned)f2bf(a.y) << 16);
  o.y = (unsigned)f2bf(a.z) | ((unsigned)f2bf(a.w) << 16);
  o.z = (unsigned)f2bf(b.x) | ((unsigned)f2bf(b.y) << 16);
  o.w = (unsigned)f2bf(b.z) | ((unsigned)f2bf(b.w) << 16);
  ((uint4*)dst)[i] = o;
}

// ---------- kernel 2: logits GEMM, output-stationary over n ----------
// One block owns a 128-row M-tile and loops all 8 n-tiles internally:
//   logits[m] = sum_n tanh( sum_k A[m][k]*W[n][k] ) * v[n]
// nt==0: read ctx fp32, convert to bf16 in-reg, ds_write (swizzled) + write
//        bf16 mirror to ws.  nt>=1: global_load_lds from the bf16 mirror
//        (L2/L3-resident; pre-swizzled per-lane global source).
// LDS tiles [128][64] bf16 with 16B-chunk XOR swizzle: slot p = s ^ (row&7)
// -> fragment ds_read_b128 and staging accesses are bank-uniform.
// Waves: 4, each owns 32 rows x 128 cols per n-tile (acc[2][8]); logit
// partials accumulate in registers across nt; single shfl reduce + direct
// store at the end (no atomics, no pre-zero).

__global__ __launch_bounds__(256, 2) void gemm_logits(
    const float* __restrict__ ctx,          // [M][1024] fp32
    const unsigned short* __restrict__ Wb,  // [1024][1024] bf16
    unsigned short* __restrict__ Abf,       // [M][1024] bf16 mirror (ws)
    const float* __restrict__ v,
    float* __restrict__ logits)             // [M]
{
  __shared__ __align__(16) unsigned short Al[128 * 64];  // 16 KB
  __shared__ __align__(16) unsigned short Wl[128 * 64];  // 16 KB

  const int t    = threadIdx.x;
  const int m0   = blockIdx.x * 128;
  const int w    = t >> 6;
  const int lane = t & 63;
  const int c    = lane & 15;      // frag row-index within 16
  const int q    = lane >> 4;      // frag k-quad
  const int wm   = w * 32;         // wave row offset in M-tile

  // staging geometry: 1024 chunks of 16B per tile; thread covers 4 rows
  const int rt   = t >> 3;         // 0..31: row part
  const int sA   = t & 7;          // global 16B-chunk index within row
  const int sx   = rt & 7;         // row&7 of this thread's staging rows
  const int psl  = sA ^ sx;        // swizzled slot (== pre-swizzled src chunk)

  float p[2][4] = {};              // logit partials [mi][reg]

  for (int nt = 0; nt < 8; ++nt) {
    const int n0 = nt * 128;
    f32x4 acc[2][8] = {};

    for (int kt = 0; kt < 16; ++kt) {
      const int k0 = kt * 64;

      if (nt == 0) {
        // fp32 load -> bf16 convert -> swizzled LDS write + linear ws mirror
#pragma unroll
        for (int j = 0; j < 4; ++j) {
          const int row = j * 32 + rt;
          const float* g = ctx + (size_t)(m0 + row) * DDIM + k0 + sA * 8;
          float4 a = *(const float4*)g;
          float4 b = *(const float4*)(g + 4);
          bf16x8 cv;
          cv[0] = (__bf16)a.x; cv[1] = (__bf16)a.y;
          cv[2] = (__bf16)a.z; cv[3] = (__bf16)a.w;
          cv[4] = (__bf16)b.x; cv[5] = (__bf16)b.y;
          cv[6] = (__bf16)b.z; cv[7] = (__bf16)b.w;
          *(bf16x8*)&Al[row * 64 + psl * 8] = cv;
          *(bf16x8*)&Abf[(size_t)(m0 + row) * DDIM + k0 + sA * 8] = cv;
        }
      } else {
        // bf16 mirror -> LDS direct; source pre-swizzled so linear LDS dest
        // ends up in the swizzled layout
#pragma unroll
        for (int r = 0; r < 4; ++r) {
          const int row = r * 32 + rt;
          gl_lds16(Abf + (size_t)(m0 + row) * DDIM + k0 + psl * 8,
                   Al + (r * 256 + (t & 192)) * 8);
        }
      }
      // W tile: same pre-swizzled gl_lds pattern
#pragma unroll
      for (int r = 0; r < 4; ++r) {
        const int row = r * 32 + rt;
        gl_lds16(Wb + (size_t)(n0 + row) * DDIM + k0 + psl * 8,
                 Wl + (r * 256 + (t & 192)) * 8);
      }
      __syncthreads();

#pragma unroll
      for (int kk = 0; kk < 2; ++kk) {
        bf16x8 af[2], bw[8];
#pragma unroll
        for (int mi = 0; mi < 2; ++mi) {
          const int row = wm + mi * 16 + c;
          af[mi] = *(const bf16x8*)&Al[row * 64 + (((kk * 4 + q) ^ (c & 7)) * 8)];
        }
#pragma unroll
        for (int ni = 0; ni < 8; ++ni) {
          const int row = ni * 16 + c;
          bw[ni] = *(const bf16x8*)&Wl[row * 64 + (((kk * 4 + q) ^ (c & 7)) * 8)];
        }
#pragma unroll
        for (int mi = 0; mi < 2; ++mi)
#pragma unroll
          for (int ni = 0; ni < 8; ++ni)
            acc[mi][ni] = __builtin_amdgcn_mfma_f32_16x16x32_bf16(
                af[mi], bw[ni], acc[mi][ni], 0, 0, 0);
      }
      __syncthreads();
    }

    // fold this n-tile into the register logit partials
#pragma unroll
    for (int ni = 0; ni < 8; ++ni) {
      const float vvn = v[n0 + ni * 16 + c];
#pragma unroll
      for (int mi = 0; mi < 2; ++mi) {
        p[mi][0] += fast_tanh(acc[mi][ni][0]) * vvn;
        p[mi][1] += fast_tanh(acc[mi][ni][1]) * vvn;
        p[mi][2] += fast_tanh(acc[mi][ni][2]) * vvn;
        p[mi][3] += fast_tanh(acc[mi][ni][3]) * vvn;
      }
    }
  }

  // reduce over the 16 c-lanes (n within frag) and store directly
#pragma unroll
  for (int mi = 0; mi < 2; ++mi)
#pragma unroll
    for (int r = 0; r < 4; ++r) {
      float x = p[mi][r];
      x += __shfl_xor(x, 1);
      x += __shfl_xor(x, 2);
      x += __shfl_xor(x, 4);
      x += __shfl_xor(x, 8);
      p[mi][r] = x;
    }
  if (c == 0) {
#pragma unroll
    for (int mi = 0; mi < 2; ++mi) {
      float4 o = {p[mi][0], p[mi][1], p[mi][2], p[mi][3]};
      *(float4*)(logits + m0 + wm + mi * 16 + q * 4) = o;
    }
  }
}

// ---------- kernel 3: per-batch softmax (in place over logits) ----------

__global__ __launch_bounds__(256) void softmax_kernel(float* __restrict__ la) {
  const int b = blockIdx.x;
  const int t = threadIdx.x;
  float* p = la + (size_t)b * SDIM;
  float x[8];
#pragma unroll
  for (int i = 0; i < 8; ++i) x[i] = p[i * 256 + t];
  float m = x[0];
#pragma unroll
  for (int i = 1; i < 8; ++i) m = fmaxf(m, x[i]);
#pragma unroll
  for (int mask = 1; mask < 64; mask <<= 1) m = fmaxf(m, __shfl_xor(m, mask));
  __shared__ float redm[4], reds[4];
  const int w = t >> 6, lane = t & 63;
  if (lane == 0) redm[w] = m;
  __syncthreads();
  m = fmaxf(fmaxf(redm[0], redm[1]), fmaxf(redm[2], redm[3]));
  float e[8];
  float s = 0.f;
#pragma unroll
  for (int i = 0; i < 8; ++i) { e[i] = __expf(x[i] - m); s += e[i]; }
#pragma unroll
  for (int mask = 1; mask < 64; mask <<= 1) s += __shfl_xor(s, mask);
  if (lane == 0) reds[w] = s;
  __syncthreads();
  s = reds[0] + reds[1] + reds[2] + reds[3];
  const float inv = 1.0f / s;
#pragma unroll
  for (int i = 0; i < 8; ++i) p[i * 256 + t] = e[i] * inv;
}

// ---------- kernel 4: weighted context partial sums (no atomics) ----------
// part[b][sc][d] = sum_{s in chunk sc} attn[b][s] * ctx[b][s][d]

__global__ __launch_bounds__(256) void wsum_part(const float* __restrict__ ctx,
                                                 const float* __restrict__ attn,
                                                 float* __restrict__ part) {
  const int b  = blockIdx.x >> 4;
  const int sc = blockIdx.x & 15;
  const int t  = threadIdx.x;
  const float* cp = ctx + ((size_t)b * SDIM + sc * 128) * DDIM + t * 4;
  const float* ap = attn + (size_t)b * SDIM + sc * 128;
  float4 acc = {0.f, 0.f, 0.f, 0.f};
  for (int s = 0; s < 128; ++s) {
    const float a = ap[s];
    const float4 cv = *(const float4*)(cp + (size_t)s * DDIM);
    acc.x += a * cv.x; acc.y += a * cv.y; acc.z += a * cv.z; acc.w += a * cv.w;
  }
  *(float4*)(part + (size_t)blockIdx.x * DDIM + t * 4) = acc;
}

// ---------- kernel 5: reduce the 16 partials per (b, d) ----------

__global__ __launch_bounds__(256) void wsum_reduce(const float* __restrict__ part,
                                                   float* __restrict__ wc) {
  const int b = blockIdx.x >> 2;
  const int d = (blockIdx.x & 3) * 256 + threadIdx.x;
  float s = 0.f;
#pragma unroll
  for (int sc = 0; sc < 16; ++sc) s += part[(size_t)(b * 16 + sc) * DDIM + d];
  wc[(size_t)b * DDIM + d] = s;
}

// ---------- launch ----------

extern "C" void kernel_launch(void* const* d_in, const int* in_sizes, int n_in,
                              void* d_out, int out_size, void* d_ws, size_t ws_size,
                              hipStream_t stream) {
  const float* ctx = (const float*)d_in[0];   // [32,2048,1024] fp32
  const float* W   = (const float*)d_in[1];   // [1024,1024] fp32
  const float* v   = (const float*)d_in[2];   // [1024] fp32
  // d_in[3] = scalar b: softmax-invariant, unused.

  float* out_wc   = (float*)d_out;            // [32,1024]
  float* out_attn = out_wc + BDIM * DDIM;     // [32,2048] (logits, then attn)

  unsigned short* W_bf   = (unsigned short*)d_ws;             // 2 MB
  unsigned short* ctx_bf = W_bf + (size_t)DDIM * DDIM;        // 128 MB bf16 mirror
  float* part = (float*)(void*)ctx_bf;        // aliases ctx_bf (dead after gemm)

  cvt_kernel<<<(DDIM * DDIM) / (256 * 8), 256, 0, stream>>>(W, W_bf);
  gemm_logits<<<MDIM / 128, 256, 0, stream>>>(ctx, W_bf, ctx_bf, v, out_attn);
  softmax_kernel<<<BDIM, 256, 0, stream>>>(out_attn);
  wsum_part<<<BDIM * 16, 256, 0, stream>>>(ctx, out_attn, part);
  wsum_reduce<<<(BDIM * DDIM) / 256, 256, 0, stream>>>(part, out_wc);
}

// Round 3
// 626.862 us; speedup vs baseline: 1.0115x; 1.0115x over previous
//
#include <hip/hip_runtime.h>
#include <stdint.h>

// Shapes (fixed by reference): B=32, S=2048, D=1024.
#define BDIM 32
#define SDIM 2048
#define DDIM 1024
#define MDIM (BDIM * SDIM)   // 65536 rows of the GEMM

typedef __bf16 bf16x8 __attribute__((ext_vector_type(8)));
typedef float  f32x4  __attribute__((ext_vector_type(4)));

// ---------- helpers ----------

__device__ inline unsigned short f2bf(float f) {
  union { float f; unsigned u; } un; un.f = f;
  unsigned r = un.u + 0x7fffu + ((un.u >> 16) & 1u);   // RNE
  return (unsigned short)(r >> 16);
}

__device__ inline float fast_tanh(float x) {
  float e = __expf(2.0f * x);
  return 1.0f - 2.0f / (e + 1.0f);
}

__device__ inline void gl_lds16(const unsigned short* g, unsigned short* l) {
  __builtin_amdgcn_global_load_lds(
      (__attribute__((address_space(1))) unsigned int*)(void*)(uintptr_t)g,
      (__attribute__((address_space(3))) unsigned int*)l,
      16, 0, 0);
}

// ---------- kernel 1: fp32 -> bf16 convert (8 elems/thread) ----------

__global__ __launch_bounds__(256) void cvt_kernel(const float* __restrict__ src,
                                                  unsigned short* __restrict__ dst) {
  size_t i = (size_t)blockIdx.x * 256 + threadIdx.x;
  const float4* s4 = (const float4*)src;
  float4 a = s4[2 * i];
  float4 b = s4[2 * i + 1];
  uint4 o;
  o.x = (unsigned)f2bf(a.x) | ((unsigned)f2bf(a.y) << 16);
  o.y = (unsigned)f2bf(a.z) | ((unsigned)f2bf(a.w) << 16);
  o.z = (unsigned)f2bf(b.x) | ((unsigned)f2bf(b.y) << 16);
  o.w = (unsigned)f2bf(b.z) | ((unsigned)f2bf(b.w) << 16);
  ((uint4*)dst)[i] = o;
}

// ---------- kernel 2: bf16 GEMM (128x128 tile, BK=64, swizzled LDS) ----------
// logits[m] += sum_n tanh( sum_k A[m][k]*W[n][k] ) * v[n]
// Grid 4096 = 512 mt x 8 nt. Bijective XCD remap (m204): hardware bid ->
// l = (bid&7)*512 + (bid>>3); mt = l>>3, nt = l&7.  The 8 nt-blocks of one
// mt then share one XCD (bids differ by 8 -> same bid%8) within 64 dispatch
// slots, so the A-panel re-reads hit that XCD's L2.
// LDS tiles [128][64] bf16, 16B-chunk XOR swizzle slot = chunk ^ (row&7):
// staged via global_load_lds with pre-swizzled per-lane SOURCE + linear dest
// (rule 21), read back with the same XOR -> 0 bank conflicts (verified r2).

__global__ __launch_bounds__(256) void gemm_logits(
    const unsigned short* __restrict__ A,   // [M][1024] bf16 context
    const unsigned short* __restrict__ Bw,  // [1024][1024] bf16 W
    const float* __restrict__ v,
    float* __restrict__ logits)             // [M], pre-zeroed
{
  __shared__ __align__(16) unsigned short Al[128 * 64];  // 16 KB
  __shared__ __align__(16) unsigned short Wl[128 * 64];  // 16 KB

  const int t  = threadIdx.x;
  const int l  = (blockIdx.x & 7) * 512 + (blockIdx.x >> 3);
  const int mt = l >> 3;
  const int nt = l & 7;
  const int m0 = mt * 128;
  const int n0 = nt * 128;
  const int w    = t >> 6;
  const int lane = t & 63;
  const int c = lane & 15;        // frag col (n within 16) / row (m within 16)
  const int q = lane >> 4;        // frag quad
  const int wm = (w >> 1) * 64;   // wave row offset in tile
  const int wn = (w & 1) * 64;    // wave col offset in tile

  // v values for this wave's 4 column-frags (epilogue)
  float vv[4];
#pragma unroll
  for (int ni = 0; ni < 4; ++ni) vv[ni] = v[n0 + wn + ni * 16 + c];

  f32x4 acc[4][4] = {};

  // staging geometry: 128 rows x 8 chunks of 16B per tile; thread -> 4 rows
  const int rt  = t >> 3;          // 0..31 row part
  const int sA  = t & 7;           // chunk index
  const int psl = sA ^ (rt & 7);   // pre-swizzled source chunk
  const unsigned short* ga = A  + (size_t)(m0 + rt) * DDIM + psl * 8;
  const unsigned short* gb = Bw + (size_t)(n0 + rt) * DDIM + psl * 8;
  unsigned short* lab = Al + (size_t)(t & 192) * 8;   // wave-uniform base
  unsigned short* lwb = Wl + (size_t)(t & 192) * 8;

  for (int kt = 0; kt < 16; ++kt) {
    const int k0 = kt * 64;
#pragma unroll
    for (int r = 0; r < 4; ++r)
      gl_lds16(ga + (size_t)(r * 32) * DDIM + k0, lab + r * 2048);
#pragma unroll
    for (int r = 0; r < 4; ++r)
      gl_lds16(gb + (size_t)(r * 32) * DDIM + k0, lwb + r * 2048);
    __syncthreads();

#pragma unroll
    for (int kk = 0; kk < 2; ++kk) {
      bf16x8 af[4], bfr[4];
      const int slot = ((kk * 4 + q) ^ (c & 7)) * 8;
#pragma unroll
      for (int mi = 0; mi < 4; ++mi)
        af[mi] = *(const bf16x8*)&Al[(wm + mi * 16 + c) * 64 + slot];
#pragma unroll
      for (int ni = 0; ni < 4; ++ni)
        bfr[ni] = *(const bf16x8*)&Wl[(wn + ni * 16 + c) * 64 + slot];
#pragma unroll
      for (int mi = 0; mi < 4; ++mi)
#pragma unroll
        for (int ni = 0; ni < 4; ++ni)
          acc[mi][ni] = __builtin_amdgcn_mfma_f32_16x16x32_bf16(
              af[mi], bfr[ni], acc[mi][ni], 0, 0, 0);
    }
    __syncthreads();
  }

  // Epilogue: tanh, dot with v over this wave's 64 columns, reduce, atomicAdd.
  // C/D layout (16x16): col = lane&15, row = (lane>>4)*4 + reg.
#pragma unroll
  for (int mi = 0; mi < 4; ++mi) {
    float p0 = 0.f, p1 = 0.f, p2 = 0.f, p3 = 0.f;
#pragma unroll
    for (int ni = 0; ni < 4; ++ni) {
      const float vvn = vv[ni];
      p0 += fast_tanh(acc[mi][ni][0]) * vvn;
      p1 += fast_tanh(acc[mi][ni][1]) * vvn;
      p2 += fast_tanh(acc[mi][ni][2]) * vvn;
      p3 += fast_tanh(acc[mi][ni][3]) * vvn;
    }
#pragma unroll
    for (int mask = 1; mask <= 8; mask <<= 1) {
      p0 += __shfl_xor(p0, mask);
      p1 += __shfl_xor(p1, mask);
      p2 += __shfl_xor(p2, mask);
      p3 += __shfl_xor(p3, mask);
    }
    if (c == 0) {
      float* lp = logits + (m0 + wm + mi * 16 + q * 4);
      atomicAdd(lp + 0, p0);
      atomicAdd(lp + 1, p1);
      atomicAdd(lp + 2, p2);
      atomicAdd(lp + 3, p3);
    }
  }
}

// ---------- kernel 3: per-batch softmax (in place over logits) ----------

__global__ __launch_bounds__(256) void softmax_kernel(float* __restrict__ la) {
  const int b = blockIdx.x;
  const int t = threadIdx.x;
  float* p = la + (size_t)b * SDIM;
  float x[8];
#pragma unroll
  for (int i = 0; i < 8; ++i) x[i] = p[i * 256 + t];
  float m = x[0];
#pragma unroll
  for (int i = 1; i < 8; ++i) m = fmaxf(m, x[i]);
#pragma unroll
  for (int mask = 1; mask < 64; mask <<= 1) m = fmaxf(m, __shfl_xor(m, mask));
  __shared__ float redm[4], reds[4];
  const int w = t >> 6, lane = t & 63;
  if (lane == 0) redm[w] = m;
  __syncthreads();
  m = fmaxf(fmaxf(redm[0], redm[1]), fmaxf(redm[2], redm[3]));
  float e[8];
  float s = 0.f;
#pragma unroll
  for (int i = 0; i < 8; ++i) { e[i] = __expf(x[i] - m); s += e[i]; }
#pragma unroll
  for (int mask = 1; mask < 64; mask <<= 1) s += __shfl_xor(s, mask);
  if (lane == 0) reds[w] = s;
  __syncthreads();
  s = reds[0] + reds[1] + reds[2] + reds[3];
  const float inv = 1.0f / s;
#pragma unroll
  for (int i = 0; i < 8; ++i) p[i * 256 + t] = e[i] * inv;
}

// ---------- kernel 4: weighted context partial sums (no atomics) ----------
// part[b][sc][d] = sum_{s in 32-row chunk sc} attn[b][s] * ctx[b][s][d]
// 2048 blocks -> 8 blocks/CU -> 32 waves/CU of TLP for the dependent FMAs.

__global__ __launch_bounds__(256) void wsum_part(const float* __restrict__ ctx,
                                                 const float* __restrict__ attn,
                                                 float* __restrict__ part) {
  const int b  = blockIdx.x >> 6;
  const int sc = blockIdx.x & 63;
  const int t  = threadIdx.x;
  const float* cp = ctx + ((size_t)b * SDIM + sc * 32) * DDIM + t * 4;
  const float* ap = attn + (size_t)b * SDIM + sc * 32;
  float4 acc = {0.f, 0.f, 0.f, 0.f};
#pragma unroll 4
  for (int s = 0; s < 32; ++s) {
    const float a = ap[s];
    const float4 cv = *(const float4*)(cp + (size_t)s * DDIM);
    acc.x += a * cv.x; acc.y += a * cv.y; acc.z += a * cv.z; acc.w += a * cv.w;
  }
  *(float4*)(part + (size_t)blockIdx.x * DDIM + t * 4) = acc;
}

// ---------- kernel 5: reduce the 64 partials per (b, d) ----------

__global__ __launch_bounds__(256) void wsum_reduce(const float* __restrict__ part,
                                                   float* __restrict__ wc) {
  const int b = blockIdx.x >> 2;
  const int d = (blockIdx.x & 3) * 256 + threadIdx.x;
  float s = 0.f;
#pragma unroll
  for (int sc = 0; sc < 64; ++sc)
    s += part[((size_t)b * 64 + sc) * DDIM + d];
  wc[(size_t)b * DDIM + d] = s;
}

// ---------- launch ----------

extern "C" void kernel_launch(void* const* d_in, const int* in_sizes, int n_in,
                              void* d_out, int out_size, void* d_ws, size_t ws_size,
                              hipStream_t stream) {
  const float* ctx = (const float*)d_in[0];   // [32,2048,1024] fp32
  const float* W   = (const float*)d_in[1];   // [1024,1024] fp32
  const float* v   = (const float*)d_in[2];   // [1024] fp32
  // d_in[3] = scalar b: softmax-invariant, unused.

  float* out_wc   = (float*)d_out;            // [32,1024]
  float* out_attn = out_wc + BDIM * DDIM;     // [32,2048] (logits, then attn)

  unsigned short* W_bf   = (unsigned short*)d_ws;             // 2 MB
  unsigned short* ctx_bf = W_bf + (size_t)DDIM * DDIM;        // 128 MB
  float* part = (float*)(void*)ctx_bf;        // aliases ctx_bf (dead after gemm)

  // zero logits (atomics target) only; wc is written by direct store
  hipMemsetAsync(out_attn, 0, (size_t)BDIM * SDIM * sizeof(float), stream);

  cvt_kernel<<<(DDIM * DDIM) / (256 * 8), 256, 0, stream>>>(W, W_bf);
  cvt_kernel<<<(MDIM * DDIM) / (256 * 8), 256, 0, stream>>>(ctx, ctx_bf);
  gemm_logits<<<(MDIM / 128) * (DDIM / 128), 256, 0, stream>>>(ctx_bf, W_bf, v, out_attn);
  softmax_kernel<<<BDIM, 256, 0, stream>>>(out_attn);
  wsum_part<<<BDIM * 64, 256, 0, stream>>>(ctx, out_attn, part);
  wsum_reduce<<<(BDIM * DDIM) / 256, 256, 0, stream>>>(part, out_wc);
}

// Round 5
// 556.979 us; speedup vs baseline: 1.1384x; 1.1255x over previous
//
#include <hip/hip_runtime.h>
#include <stdint.h>

// Shapes (fixed by reference): B=32, S=2048, D=1024.
#define BDIM 32
#define SDIM 2048
#define DDIM 1024
#define MDIM (BDIM * SDIM)   // 65536 rows of the GEMM

typedef __bf16 bf16x8 __attribute__((ext_vector_type(8)));
typedef float  f32x4  __attribute__((ext_vector_type(4)));

// ---------- helpers ----------

__device__ inline unsigned short f2bf(float f) {
  union { float f; unsigned u; } un; un.f = f;
  unsigned r = un.u + 0x7fffu + ((un.u >> 16) & 1u);   // RNE
  return (unsigned short)(r >> 16);
}

__device__ inline float fast_tanh(float x) {
  float e = __expf(2.0f * x);
  return 1.0f - 2.0f / (e + 1.0f);
}

__device__ inline void gl_lds16(const unsigned short* g, unsigned short* l) {
  __builtin_amdgcn_global_load_lds(
      (__attribute__((address_space(1))) unsigned int*)(void*)(uintptr_t)g,
      (__attribute__((address_space(3))) unsigned int*)l,
      16, 0, 0);
}

// ---------- kernel 1: fp32 -> bf16 convert (W only, 8 elems/thread) ----------

__global__ __launch_bounds__(256) void cvt_kernel(const float* __restrict__ src,
                                                  unsigned short* __restrict__ dst) {
  size_t i = (size_t)blockIdx.x * 256 + threadIdx.x;
  const float4* s4 = (const float4*)src;
  float4 a = s4[2 * i];
  float4 b = s4[2 * i + 1];
  uint4 o;
  o.x = (unsigned)f2bf(a.x) | ((unsigned)f2bf(a.y) << 16);
  o.y = (unsigned)f2bf(a.z) | ((unsigned)f2bf(a.w) << 16);
  o.z = (unsigned)f2bf(b.x) | ((unsigned)f2bf(b.y) << 16);
  o.w = (unsigned)f2bf(b.z) | ((unsigned)f2bf(b.w) << 16);
  ((uint4*)dst)[i] = o;
}

// ---------- kernel 2: fused cvt+GEMM (128x128 tile, BK=64, swizzled LDS) ----
// logitsP[nt*2+(w&1)][m] = sum_{n in wave's 64-col half} tanh(...) * v[n]
// Each wave owns a 64x64 quadrant: waves sharing rows write DIFFERENT planes
// (16 planes total) -- fixes round-4's wave-collision overwrite.
// ctx is read fp32 and converted to bf16 in-kernel (reg-staged, swizzled
// ds_write; refcheck-verified round 2) -- standalone 384 MB cvt eliminated.
// W staged via global_load_lds with pre-swizzled per-lane source (rule 21).
// Grid 4096 = 512 mt x 8 nt, bijective XCD remap l=(bid&7)*512+(bid>>3):
// the 8 nt-blocks of one mt share an XCD -> fp32 A-panel L2-resident for
// the 7 re-reads (round-3 FETCH 87 MB validated this locality).
// LDS [128][64] bf16, 16B-chunk XOR swizzle: 0 bank conflicts (r2/r3).

__global__ __launch_bounds__(256) void gemm_logits(
    const float* __restrict__ ctx,          // [M][1024] fp32
    const unsigned short* __restrict__ Bw,  // [1024][1024] bf16 W
    const float* __restrict__ v,
    float* __restrict__ logitsP)            // [16][M] partial planes
{
  __shared__ __align__(16) unsigned short Al[128 * 64];  // 16 KB
  __shared__ __align__(16) unsigned short Wl[128 * 64];  // 16 KB

  const int t  = threadIdx.x;
  const int l  = (blockIdx.x & 7) * 512 + (blockIdx.x >> 3);
  const int mt = l >> 3;
  const int nt = l & 7;
  const int m0 = mt * 128;
  const int n0 = nt * 128;
  const int w    = t >> 6;
  const int lane = t & 63;
  const int c = lane & 15;        // frag col/row within 16
  const int q = lane >> 4;        // frag quad
  const int wm = (w >> 1) * 64;   // wave row offset in tile
  const int wn = (w & 1) * 64;    // wave col offset in tile

  // v values for this wave's 4 column-frags (epilogue)
  float vv[4];
#pragma unroll
  for (int ni = 0; ni < 4; ++ni) vv[ni] = v[n0 + wn + ni * 16 + c];

  f32x4 acc[4][4] = {};

  // staging geometry: 128 rows x 8 chunks of 16B(bf16)/32B(fp32) per tile
  const int rt  = t >> 3;          // 0..31 row part
  const int sA  = t & 7;           // chunk index
  const int psl = sA ^ (rt & 7);   // swizzled slot (== pre-swizzled src chunk)
  const float* gA = ctx + (size_t)(m0 + rt) * DDIM + sA * 8;   // fp32, linear
  const unsigned short* gb = Bw + (size_t)(n0 + rt) * DDIM + psl * 8;
  unsigned short* lwb = Wl + (size_t)(t & 192) * 8;   // wave-uniform base

  for (int kt = 0; kt < 16; ++kt) {
    const int k0 = kt * 64;
    // W: async global->LDS, pre-swizzled source, linear dest
#pragma unroll
    for (int r = 0; r < 4; ++r)
      gl_lds16(gb + (size_t)(r * 32) * DDIM + k0, lwb + r * 2048);
    // A: fp32 load -> bf16 cvt -> swizzled ds_write
#pragma unroll
    for (int j = 0; j < 4; ++j) {
      const int row = j * 32 + rt;
      const float* g = gA + (size_t)(j * 32) * DDIM + k0;
      float4 a = *(const float4*)g;
      float4 b = *(const float4*)(g + 4);
      bf16x8 cv;
      cv[0] = (__bf16)a.x; cv[1] = (__bf16)a.y;
      cv[2] = (__bf16)a.z; cv[3] = (__bf16)a.w;
      cv[4] = (__bf16)b.x; cv[5] = (__bf16)b.y;
      cv[6] = (__bf16)b.z; cv[7] = (__bf16)b.w;
      *(bf16x8*)&Al[row * 64 + psl * 8] = cv;
    }
    __syncthreads();

#pragma unroll
    for (int kk = 0; kk < 2; ++kk) {
      bf16x8 af[4], bfr[4];
      const int slot = ((kk * 4 + q) ^ (c & 7)) * 8;
#pragma unroll
      for (int mi = 0; mi < 4; ++mi)
        af[mi] = *(const bf16x8*)&Al[(wm + mi * 16 + c) * 64 + slot];
#pragma unroll
      for (int ni = 0; ni < 4; ++ni)
        bfr[ni] = *(const bf16x8*)&Wl[(wn + ni * 16 + c) * 64 + slot];
#pragma unroll
      for (int mi = 0; mi < 4; ++mi)
#pragma unroll
        for (int ni = 0; ni < 4; ++ni)
          acc[mi][ni] = __builtin_amdgcn_mfma_f32_16x16x32_bf16(
              af[mi], bfr[ni], acc[mi][ni], 0, 0, 0);
    }
    __syncthreads();
  }

  // Epilogue: tanh, dot with v over this wave's 64 columns, shfl-reduce over
  // the 16 c-lanes, store to this wave's own plane (no atomics, no overlap).
  // C/D layout (16x16): col = lane&15, row = (lane>>4)*4 + reg.
  const size_t plane = (size_t)(nt * 2 + (w & 1)) * MDIM;
#pragma unroll
  for (int mi = 0; mi < 4; ++mi) {
    float p0 = 0.f, p1 = 0.f, p2 = 0.f, p3 = 0.f;
#pragma unroll
    for (int ni = 0; ni < 4; ++ni) {
      const float vvn = vv[ni];
      p0 += fast_tanh(acc[mi][ni][0]) * vvn;
      p1 += fast_tanh(acc[mi][ni][1]) * vvn;
      p2 += fast_tanh(acc[mi][ni][2]) * vvn;
      p3 += fast_tanh(acc[mi][ni][3]) * vvn;
    }
#pragma unroll
    for (int mask = 1; mask <= 8; mask <<= 1) {
      p0 += __shfl_xor(p0, mask);
      p1 += __shfl_xor(p1, mask);
      p2 += __shfl_xor(p2, mask);
      p3 += __shfl_xor(p3, mask);
    }
    if (c == 0) {
      float4 o = {p0, p1, p2, p3};
      *(float4*)(logitsP + plane + m0 + wm + mi * 16 + q * 4) = o;
    }
  }
}

// ---------- kernel 3: plane-sum (16 planes) + per-batch softmax ----------

__global__ __launch_bounds__(256) void softmax_kernel(const float* __restrict__ P,
                                                      float* __restrict__ attn) {
  const int b = blockIdx.x;
  const int t = threadIdx.x;
  float x[8];
#pragma unroll
  for (int i = 0; i < 8; ++i) {
    const size_t off = (size_t)b * SDIM + i * 256 + t;
    float s = 0.f;
#pragma unroll
    for (int pl = 0; pl < 16; ++pl) s += P[(size_t)pl * MDIM + off];
    x[i] = s;
  }
  float m = x[0];
#pragma unroll
  for (int i = 1; i < 8; ++i) m = fmaxf(m, x[i]);
#pragma unroll
  for (int mask = 1; mask < 64; mask <<= 1) m = fmaxf(m, __shfl_xor(m, mask));
  __shared__ float redm[4], reds[4];
  const int w = t >> 6, lane = t & 63;
  if (lane == 0) redm[w] = m;
  __syncthreads();
  m = fmaxf(fmaxf(redm[0], redm[1]), fmaxf(redm[2], redm[3]));
  float e[8];
  float s = 0.f;
#pragma unroll
  for (int i = 0; i < 8; ++i) { e[i] = __expf(x[i] - m); s += e[i]; }
#pragma unroll
  for (int mask = 1; mask < 64; mask <<= 1) s += __shfl_xor(s, mask);
  if (lane == 0) reds[w] = s;
  __syncthreads();
  s = reds[0] + reds[1] + reds[2] + reds[3];
  const float inv = 1.0f / s;
  float* p = attn + (size_t)b * SDIM;
#pragma unroll
  for (int i = 0; i < 8; ++i) p[i * 256 + t] = e[i] * inv;
}

// ---------- kernel 4: weighted context partial sums (no atomics) ----------
// part[b][sc][d] = sum_{s in 32-row chunk sc} attn[b][s] * ctx[b][s][d]

__global__ __launch_bounds__(256) void wsum_part(const float* __restrict__ ctx,
                                                 const float* __restrict__ attn,
                                                 float* __restrict__ part) {
  const int b  = blockIdx.x >> 6;
  const int sc = blockIdx.x & 63;
  const int t  = threadIdx.x;
  const float* cp = ctx + ((size_t)b * SDIM + sc * 32) * DDIM + t * 4;
  const float* ap = attn + (size_t)b * SDIM + sc * 32;
  float4 acc = {0.f, 0.f, 0.f, 0.f};
#pragma unroll 4
  for (int s = 0; s < 32; ++s) {
    const float a = ap[s];
    const float4 cv = *(const float4*)(cp + (size_t)s * DDIM);
    acc.x += a * cv.x; acc.y += a * cv.y; acc.z += a * cv.z; acc.w += a * cv.w;
  }
  *(float4*)(part + (size_t)blockIdx.x * DDIM + t * 4) = acc;
}

// ---------- kernel 5: reduce the 64 partials per (b, d) ----------

__global__ __launch_bounds__(256) void wsum_reduce(const float* __restrict__ part,
                                                   float* __restrict__ wc) {
  const int b = blockIdx.x >> 2;
  const int d = (blockIdx.x & 3) * 256 + threadIdx.x;
  float s = 0.f;
#pragma unroll
  for (int sc = 0; sc < 64; ++sc)
    s += part[((size_t)b * 64 + sc) * DDIM + d];
  wc[(size_t)b * DDIM + d] = s;
}

// ---------- launch ----------

extern "C" void kernel_launch(void* const* d_in, const int* in_sizes, int n_in,
                              void* d_out, int out_size, void* d_ws, size_t ws_size,
                              hipStream_t stream) {
  const float* ctx = (const float*)d_in[0];   // [32,2048,1024] fp32
  const float* W   = (const float*)d_in[1];   // [1024,1024] fp32
  const float* v   = (const float*)d_in[2];   // [1024] fp32
  // d_in[3] = scalar b: softmax-invariant, unused.

  float* out_wc   = (float*)d_out;            // [32,1024]
  float* out_attn = out_wc + BDIM * DDIM;     // [32,2048]

  float* logitsP = (float*)d_ws;                         // [16][M] = 4 MB
  float* part    = logitsP + (size_t)16 * MDIM;          // [2048][1024] = 8 MB
  unsigned short* W_bf = (unsigned short*)(part + (size_t)2048 * DDIM);  // 2 MB

  cvt_kernel<<<(DDIM * DDIM) / (256 * 8), 256, 0, stream>>>(W, W_bf);
  gemm_logits<<<(MDIM / 128) * (DDIM / 128), 256, 0, stream>>>(ctx, W_bf, v, logitsP);
  softmax_kernel<<<BDIM, 256, 0, stream>>>(logitsP, out_attn);
  wsum_part<<<BDIM * 64, 256, 0, stream>>>(ctx, out_attn, part);
  wsum_reduce<<<(BDIM * DDIM) / 256, 256, 0, stream>>>(part, out_wc);
}